// Round 5
// baseline (388.645 us; speedup 1.0000x reference)
//
#include <hip/hip_runtime.h>
#include <hip/hip_bf16.h>

// WindowAttention fused kernel v8 (MI355X / gfx950)
// One block = one window. 4 waves, wave = head everywhere.
// v8 = v7 + phase-1 HALF-SPLIT to kill the xa remat:
//  - xa live-set halved: xa2[2][4] (32 regs) per half, loaded as ONE wide
//    batch (16 b128 in flight), then all 6 weight tiles consumed against it.
//    v3/v7's xa[4][4] (64 regs) made the allocator remat x from global in
//    tiny serialized batches (VGPR=64 tell; ~74k stall cyc/wave accounted).
//  - per-ni ILP stays 2 independent 4-MFMA chains (v6 lesson: 1 chain kills).
//  - wf reloaded per half (12 vs 6 batches): 16B L2-hot loads, cheap.
//  - bias loads hoisted out of the ni loop.
//  - everything else identical to v7 (pre-shifted mask, deferred norm,
//    merged ph2+3, K/O alias, V in regs, launch_bounds(256,4), 32KB LDS).

#define T49  49
#define CDIM 128
#define NW   64
#define SCALEF 0.17677669529663689f   // 1/sqrt(32)

typedef short bf16x8 __attribute__((ext_vector_type(8)));
typedef float f32x4  __attribute__((ext_vector_type(4)));

union B8 { unsigned int u[4]; bf16x8 v; };

__device__ __forceinline__ unsigned int pk2(float a, float b) {
  __hip_bfloat162 h = __float22bfloat162_rn(make_float2(a, b));
  unsigned int u;
  __builtin_memcpy(&u, &h, 4);
  return u;
}

__device__ __forceinline__ unsigned short f2bf(float f) {
  unsigned int u = __builtin_bit_cast(unsigned int, f);
  u += 0x7fffu + ((u >> 16) & 1u);
  return (unsigned short)(u >> 16);
}

// prep: bf16 weights + padded mask maskp[64][64 q][64 key]
//   maskp[w][q][k] = mask - rowmax(mask)  (q<49,k<49)
//                  = -1e30                (q<49,k>=49)  -> exp()=0 exactly
//                  = 0                    (q>=49)       -> finite garbage, unused
__global__ void prep_kernel(const float* __restrict__ wq, const float* __restrict__ wp,
                            const float* __restrict__ mask,
                            short* __restrict__ wq_bf, short* __restrict__ wp_bf,
                            float* __restrict__ maskp) {
  const int i = blockIdx.x * 256 + threadIdx.x;      // grid covers 262144
  const int w = i >> 12, q = (i >> 6) & 63, k = i & 63;
  // one wave == one (w,q) row, lane == k  (256 % 64 == 0)
  float val = -3.0e38f;
  if (q < T49 && k < T49) val = mask[(w * T49 + q) * T49 + k];
  float rm = val;
  rm = fmaxf(rm, __shfl_xor(rm, 1, 64));
  rm = fmaxf(rm, __shfl_xor(rm, 2, 64));
  rm = fmaxf(rm, __shfl_xor(rm, 4, 64));
  rm = fmaxf(rm, __shfl_xor(rm, 8, 64));
  rm = fmaxf(rm, __shfl_xor(rm, 16, 64));
  rm = fmaxf(rm, __shfl_xor(rm, 32, 64));
  float mv;
  if (q >= T49)      mv = 0.0f;
  else if (k >= T49) mv = -1e30f;
  else               mv = val - rm;
  maskp[i] = mv;
  if (i < 3 * CDIM * CDIM) wq_bf[i] = (short)f2bf(wq[i]);
  if (i < CDIM * CDIM)     wp_bf[i] = (short)f2bf(wp[i]);
}

__global__ __launch_bounds__(256, 4)
void winattn_kernel(const float* __restrict__ x, const float* __restrict__ maskp,
                    const float* __restrict__ b_qkv, const float* __restrict__ b_proj,
                    const short* __restrict__ wq, const short* __restrict__ wp,
                    float* __restrict__ out) {
  // LDS (32 KB):
  //  Q  [4h][64 t][32 d] bf16 @ 0      (16 KB) swz: dbyte ^ ((t&3)<<4)
  //  K  [4h][64 t][32 d] bf16 @ 16384  (16 KB) same swz; aliased by O after barrier
  //  O  [64 t][128 ch]   bf16 @ 16384  (16 KB) swz: chbyte ^ ((t&7)<<5)
  //  V: registers only (pkV)
  __shared__ __align__(16) char smem[32768];
  constexpr int Q_BASE = 0, KO_BASE = 16384;

  const int bw    = blockIdx.x;
  const int wv    = threadIdx.x >> 6;
  const int lane  = threadIdx.x & 63;
  const int g     = lane >> 4;
  const int j16   = lane & 15;
  const int wmask = bw & (NW - 1);

  // ---------------- bias prefetch (hoisted) ----------------
  float4 bQK[4];
#pragma unroll
  for (int ni = 0; ni < 4; ++ni) {
    const int ct = (ni < 2) ? (wv * 2 + ni) : (8 + wv * 2 + (ni - 2));
    bQK[ni] = *(const float4*)(b_qkv + ct * 16 + g * 4);
  }
  float bV[2];
#pragma unroll
  for (int vi = 0; vi < 2; ++vi)
    bV[vi] = b_qkv[(16 + wv * 2 + vi) * 16 + j16];

  // ---------------- Phase 1: QKV, two token-tile halves ----------------
  unsigned int pkV[2][4][2];  // [d-tile vi][tt][pair]: pairs along token (natural D[t][c])
  const float* xb = x + (size_t)bw * (T49 * CDIM);

#pragma unroll
  for (int hf = 0; hf < 2; ++hf) {
    // one wide load batch: 16 b128 loads in flight, then converts
    bf16x8 xa2[2][4];         // 32 regs, live across the 6-ni loop below
#pragma unroll
    for (int tt2 = 0; tt2 < 2; ++tt2) {
      const int t = (hf * 2 + tt2) * 16 + j16;
#pragma unroll
      for (int kt = 0; kt < 4; ++kt) {
        B8 u;
        if (t < T49) {
          const float* p = xb + t * CDIM + kt * 32 + g * 8;
          const float4 v0 = *(const float4*)p;
          const float4 v1 = *(const float4*)(p + 4);
          u.u[0] = pk2(v0.x, v0.y); u.u[1] = pk2(v0.z, v0.w);
          u.u[2] = pk2(v1.x, v1.y); u.u[3] = pk2(v1.z, v1.w);
        } else {
          u.u[0] = u.u[1] = u.u[2] = u.u[3] = 0u;
        }
        xa2[tt2][kt] = u.v;
      }
    }

#pragma unroll
    for (int ni = 0; ni < 6; ++ni) {
      const int ct = (ni < 2) ? (wv * 2 + ni)
                   : (ni < 4) ? (8 + wv * 2 + (ni - 2))
                              : (16 + wv * 2 + (ni - 4));
      bf16x8 wf[4];           // w frag: row c=ct*16+j16, k=kt*32+g*8..+7 (L2-hot)
#pragma unroll
      for (int kt = 0; kt < 4; ++kt)
        wf[kt] = *(const bf16x8*)(wq + (ct * 16 + j16) * CDIM + kt * 32 + g * 8);

      if (ni < 4) {
        // swapped: D[c][t]; 4 regs = consecutive channels -> b64 store into [t][d]
        const bool  isQ = (ni < 2);
        const float sc  = isQ ? SCALEF : 1.0f;        // fold q-scale into Q
        const float4 b4 = bQK[ni];
        const int   d0  = (ct * 16 + g * 4) & 31;
        char* base = smem + (isQ ? Q_BASE : KO_BASE) + wv * 4096;
#pragma unroll
        for (int tt2 = 0; tt2 < 2; ++tt2) {
          f32x4 acc = {0.f, 0.f, 0.f, 0.f};
#pragma unroll
          for (int kt = 0; kt < 4; ++kt)
            acc = __builtin_amdgcn_mfma_f32_16x16x32_bf16(wf[kt], xa2[tt2][kt], acc, 0, 0, 0);
          const int t = (hf * 2 + tt2) * 16 + j16;
          const uint2 w2 = make_uint2(pk2(fmaf(acc[0], sc, b4.x * sc), fmaf(acc[1], sc, b4.y * sc)),
                                      pk2(fmaf(acc[2], sc, b4.z * sc), fmaf(acc[3], sc, b4.w * sc)));
          *(uint2*)(base + t * 64 + ((d0 * 2) ^ ((t & 3) << 4))) = w2;
        }
      } else {
        // V natural: D[t][c] -> registers (pairs along token)
        const int   vi   = ni - 4;
        const float bias = bV[vi];
#pragma unroll
        for (int tt2 = 0; tt2 < 2; ++tt2) {
          f32x4 acc = {0.f, 0.f, 0.f, 0.f};
#pragma unroll
          for (int kt = 0; kt < 4; ++kt)
            acc = __builtin_amdgcn_mfma_f32_16x16x32_bf16(xa2[tt2][kt], wf[kt], acc, 0, 0, 0);
          const int tt = hf * 2 + tt2;
          pkV[vi][tt][0] = pk2(acc[0] + bias, acc[1] + bias);
          pkV[vi][tt][1] = pk2(acc[2] + bias, acc[3] + bias);
        }
      }
    }
  }
  // NO barrier: kb/qb loads below read only this wave's own writes.

  // ---------------- Prologue: kb, qb from own LDS; va from pkV ----------------
  const int gh   = g >> 1;
  const int srcA = (((2 * g    ) & 3) << 4) | j16;
  const int srcB = (((2 * g + 1) & 3) << 4) | j16;

  const char* Kb = smem + KO_BASE + wv * 4096;
  const char* Qb = smem + Q_BASE  + wv * 4096;
  bf16x8 kb[4], qb[4];
#pragma unroll
  for (int mt = 0; mt < 4; ++mt) {
    const int t = mt * 16 + j16;
    kb[mt] = *(const bf16x8*)(Kb + t * 64 + ((g * 16) ^ ((t & 3) << 4)));
    qb[mt] = *(const bf16x8*)(Qb + t * 64 + ((g * 16) ^ ((t & 3) << 4)));
  }

  // va[dt][ks] elem e wants V[key=ks*32+8g+e][d=dt*16+j16]: source tile
  // tt = 2ks + (g>>1), lane (2g+(e>>2))&3 group, pair (e&3)>>1.
  bf16x8 va[2][2];
#pragma unroll
  for (int dt = 0; dt < 2; ++dt)
#pragma unroll
    for (int ks = 0; ks < 2; ++ks) {
      const unsigned int a0  = (unsigned)__shfl((int)pkV[dt][2 * ks    ][0], srcA, 64);
      const unsigned int a0h = (unsigned)__shfl((int)pkV[dt][2 * ks + 1][0], srcA, 64);
      const unsigned int a1  = (unsigned)__shfl((int)pkV[dt][2 * ks    ][1], srcA, 64);
      const unsigned int a1h = (unsigned)__shfl((int)pkV[dt][2 * ks + 1][1], srcA, 64);
      const unsigned int b0  = (unsigned)__shfl((int)pkV[dt][2 * ks    ][0], srcB, 64);
      const unsigned int b0h = (unsigned)__shfl((int)pkV[dt][2 * ks + 1][0], srcB, 64);
      const unsigned int b1  = (unsigned)__shfl((int)pkV[dt][2 * ks    ][1], srcB, 64);
      const unsigned int b1h = (unsigned)__shfl((int)pkV[dt][2 * ks + 1][1], srcB, 64);
      B8 u;
      u.u[0] = gh ? a0h : a0;
      u.u[1] = gh ? a1h : a1;
      u.u[2] = gh ? b0h : b0;
      u.u[3] = gh ? b1h : b1;
      va[dt][ks] = u.v;
    }

  __syncthreads();   // all Q/K reads done in-registers -> O may overwrite K region

  // ---------------- Phases 2+3 merged, per q-tile nt (wave = head) ----------------
  char*        Ob  = smem + KO_BASE;
  const float* mwb = maskp + wmask * 4096;

#pragma unroll
  for (int nt = 0; nt < 4; ++nt) {
    const float* mp = mwb + (nt * 16 + j16) * 64 + g * 4;
    float4 m4[4];
#pragma unroll
    for (int mt = 0; mt < 4; ++mt) m4[mt] = *(const float4*)(mp + mt * 16);

    const f32x4 zero = {0.f, 0.f, 0.f, 0.f};
    float v[4][4];
#pragma unroll
    for (int mt = 0; mt < 4; ++mt) {
      const f32x4 s = __builtin_amdgcn_mfma_f32_16x16x32_bf16(kb[mt], qb[nt], zero, 0, 0, 0);
      // mask is pre-shifted by row max: exp directly, no max pass
      v[mt][0] = __expf(s[0] + m4[mt].x); v[mt][1] = __expf(s[1] + m4[mt].y);
      v[mt][2] = __expf(s[2] + m4[mt].z); v[mt][3] = __expf(s[3] + m4[mt].w);
    }
    // denominator chain (overlaps P-redistribute + PV below)
    float sr[8];
#pragma unroll
    for (int mt = 0; mt < 4; ++mt) {
      sr[2 * mt]     = v[mt][0] + v[mt][1];
      sr[2 * mt + 1] = v[mt][2] + v[mt][3];
    }
    float sum = ((sr[0] + sr[1]) + (sr[2] + sr[3])) + ((sr[4] + sr[5]) + (sr[6] + sr[7]));
    sum += __shfl_xor(sum, 16, 64);
    sum += __shfl_xor(sum, 32, 64);
    const float inv = 1.0f / sum;

    // P^T raw (unnormalized): pairs along key, 8 regs
    unsigned int pkn[4][2];
#pragma unroll
    for (int mt = 0; mt < 4; ++mt) {
      pkn[mt][0] = pk2(v[mt][0], v[mt][1]);
      pkn[mt][1] = pk2(v[mt][2], v[mt][3]);
    }

    // redistribute P^T + PV MFMAs
    f32x4 oacc[2] = {{0.f,0.f,0.f,0.f},{0.f,0.f,0.f,0.f}};
#pragma unroll
    for (int ks = 0; ks < 2; ++ks) {
      const unsigned int p00 = (unsigned)__shfl((int)pkn[2*ks  ][0], srcA, 64);
      const unsigned int p10 = (unsigned)__shfl((int)pkn[2*ks+1][0], srcA, 64);
      const unsigned int p01 = (unsigned)__shfl((int)pkn[2*ks  ][1], srcA, 64);
      const unsigned int p11 = (unsigned)__shfl((int)pkn[2*ks+1][1], srcA, 64);
      const unsigned int q00 = (unsigned)__shfl((int)pkn[2*ks  ][0], srcB, 64);
      const unsigned int q10 = (unsigned)__shfl((int)pkn[2*ks+1][0], srcB, 64);
      const unsigned int q01 = (unsigned)__shfl((int)pkn[2*ks  ][1], srcB, 64);
      const unsigned int q11 = (unsigned)__shfl((int)pkn[2*ks+1][1], srcB, 64);
      B8 bf;
      bf.u[0] = gh ? p10 : p00;
      bf.u[1] = gh ? p11 : p01;
      bf.u[2] = gh ? q10 : q00;
      bf.u[3] = gh ? q11 : q01;
#pragma unroll
      for (int dt = 0; dt < 2; ++dt)
        oacc[dt] = __builtin_amdgcn_mfma_f32_16x16x32_bf16(va[dt][ks], bf.v, oacc[dt], 0, 0, 0);
    }

    // deferred normalization: O = inv * (P_raw . V); lane's j16 == q on both sides
    const int to = nt * 16 + j16;
    const int sw = (to & 7) << 5;
#pragma unroll
    for (int dt = 0; dt < 2; ++dt) {
      const int ch0 = wv * 32 + dt * 16 + g * 4;
      const uint2 w2 = make_uint2(pk2(oacc[dt][0] * inv, oacc[dt][1] * inv),
                                  pk2(oacc[dt][2] * inv, oacc[dt][3] * inv));
      *(uint2*)(Ob + to * 256 + ((ch0 * 2) ^ sw)) = w2;
    }
  }
  __syncthreads();

  // ---------------- Phase 4: out = O @ wp^T + b ----------------
  {
    const char* Ob2 = smem + KO_BASE;
    bf16x8 oa[4][4];
#pragma unroll
    for (int mt = 0; mt < 4; ++mt) {
      const int t = mt * 16 + j16;
      const int sw = (t & 7) << 5;
#pragma unroll
      for (int kt = 0; kt < 4; ++kt)
        oa[mt][kt] = *(const bf16x8*)(Ob2 + t * 256 + ((kt * 64 + g * 16) ^ sw));
    }
    float* ob = out + (size_t)bw * (T49 * CDIM);
#pragma unroll
    for (int ntl = 0; ntl < 2; ++ntl) {
      const int c = (wv * 2 + ntl) * 16 + j16;
      bf16x8 bfr[4];
#pragma unroll
      for (int kt = 0; kt < 4; ++kt)
        bfr[kt] = *(const bf16x8*)(wp + c * CDIM + kt * 32 + g * 8);
      const float bias = b_proj[c];
#pragma unroll
      for (int mt = 0; mt < 4; ++mt) {
        f32x4 acc = {0.f, 0.f, 0.f, 0.f};
#pragma unroll
        for (int kt = 0; kt < 4; ++kt)
          acc = __builtin_amdgcn_mfma_f32_16x16x32_bf16(oa[mt][kt], bfr[kt], acc, 0, 0, 0);
#pragma unroll
        for (int r = 0; r < 4; ++r) {
          const int t = mt * 16 + g * 4 + r;
          if (t < T49) ob[t * CDIM + c] = acc[r] + bias;
        }
      }
    }
  }
}

extern "C" void kernel_launch(void* const* d_in, const int* in_sizes, int n_in,
                              void* d_out, int out_size, void* d_ws, size_t ws_size,
                              hipStream_t stream) {
  const float* x      = (const float*)d_in[0];
  const float* mask   = (const float*)d_in[1];
  const float* w_qkv  = (const float*)d_in[2];
  const float* b_qkv  = (const float*)d_in[3];
  const float* w_proj = (const float*)d_in[4];
  const float* b_proj = (const float*)d_in[5];
  float* out = (float*)d_out;

  float* maskp = (float*)d_ws;                       // 64*64*64 f32 = 1 MB
  short* wq_bf = (short*)((char*)d_ws + 64*64*64*4); // 96 KB
  short* wp_bf = wq_bf + 3 * CDIM * CDIM;            // 32 KB

  hipLaunchKernelGGL(prep_kernel, dim3(1024), dim3(256), 0, stream,
                     w_qkv, w_proj, mask, wq_bf, wp_bf, maskp);
  hipLaunchKernelGGL(winattn_kernel, dim3(8192), dim3(256), 0, stream,
                     x, maskp, b_qkv, b_proj, wq_bf, wp_bf, out);
}

// Round 6
// 294.339 us; speedup vs baseline: 1.3204x; 1.3204x over previous
//
#include <hip/hip_runtime.h>
#include <hip/hip_bf16.h>

// WindowAttention fused kernel v9 (MI355X / gfx950)
// One block = one window. 4 waves, wave = head everywhere.
// v9 = v7 (best: 318us) + ONE change: amdgpu_waves_per_eu(4,4).
//  Diagnosis: VGPR_Count pinned at 64 across v3/v6/v7/v8 = the backend's
//  occupancy heuristic targeting 8 waves/EU (512/8=64) even though the 32KB
//  LDS caps us at 4-5 blocks/CU. launch_bounds' 2nd arg is only a MIN; the
//  allocator squeezed into 64 regs by rematerializing xa[4][4] from GLOBAL
//  (+reconverting) on every consumer path -> serialized loads, ~74k stall
//  cyc/wave. waves_per_eu(4,4) pins occupancy to what LDS allows anyway,
//  raising the register budget to 128 so xa stays resident.
//  Everything else byte-identical to v7.

#define T49  49
#define CDIM 128
#define NW   64
#define SCALEF 0.17677669529663689f   // 1/sqrt(32)

typedef short bf16x8 __attribute__((ext_vector_type(8)));
typedef float f32x4  __attribute__((ext_vector_type(4)));

union B8 { unsigned int u[4]; bf16x8 v; };

__device__ __forceinline__ unsigned int pk2(float a, float b) {
  __hip_bfloat162 h = __float22bfloat162_rn(make_float2(a, b));
  unsigned int u;
  __builtin_memcpy(&u, &h, 4);
  return u;
}

__device__ __forceinline__ unsigned short f2bf(float f) {
  unsigned int u = __builtin_bit_cast(unsigned int, f);
  u += 0x7fffu + ((u >> 16) & 1u);
  return (unsigned short)(u >> 16);
}

// prep: bf16 weights + padded mask maskp[64][64 q][64 key]
//   maskp[w][q][k] = mask - rowmax(mask)  (q<49,k<49)
//                  = -1e30                (q<49,k>=49)  -> exp()=0 exactly
//                  = 0                    (q>=49)       -> finite garbage, unused
__global__ void prep_kernel(const float* __restrict__ wq, const float* __restrict__ wp,
                            const float* __restrict__ mask,
                            short* __restrict__ wq_bf, short* __restrict__ wp_bf,
                            float* __restrict__ maskp) {
  const int i = blockIdx.x * 256 + threadIdx.x;      // grid covers 262144
  const int w = i >> 12, q = (i >> 6) & 63, k = i & 63;
  // one wave == one (w,q) row, lane == k  (256 % 64 == 0)
  float val = -3.0e38f;
  if (q < T49 && k < T49) val = mask[(w * T49 + q) * T49 + k];
  float rm = val;
  rm = fmaxf(rm, __shfl_xor(rm, 1, 64));
  rm = fmaxf(rm, __shfl_xor(rm, 2, 64));
  rm = fmaxf(rm, __shfl_xor(rm, 4, 64));
  rm = fmaxf(rm, __shfl_xor(rm, 8, 64));
  rm = fmaxf(rm, __shfl_xor(rm, 16, 64));
  rm = fmaxf(rm, __shfl_xor(rm, 32, 64));
  float mv;
  if (q >= T49)      mv = 0.0f;
  else if (k >= T49) mv = -1e30f;
  else               mv = val - rm;
  maskp[i] = mv;
  if (i < 3 * CDIM * CDIM) wq_bf[i] = (short)f2bf(wq[i]);
  if (i < CDIM * CDIM)     wp_bf[i] = (short)f2bf(wp[i]);
}

__global__ __launch_bounds__(256)
__attribute__((amdgpu_waves_per_eu(4, 4)))
void winattn_kernel(const float* __restrict__ x, const float* __restrict__ maskp,
                    const float* __restrict__ b_qkv, const float* __restrict__ b_proj,
                    const short* __restrict__ wq, const short* __restrict__ wp,
                    float* __restrict__ out) {
  // LDS (32 KB):
  //  Q  [4h][64 t][32 d] bf16 @ 0      (16 KB) swz: dbyte ^ ((t&3)<<4)
  //  K  [4h][64 t][32 d] bf16 @ 16384  (16 KB) same swz; aliased by O after barrier
  //  O  [64 t][128 ch]   bf16 @ 16384  (16 KB) swz: chbyte ^ ((t&7)<<5)
  //  V: registers only (pkV)
  __shared__ __align__(16) char smem[32768];
  constexpr int Q_BASE = 0, KO_BASE = 16384;

  const int bw    = blockIdx.x;
  const int wv    = threadIdx.x >> 6;
  const int lane  = threadIdx.x & 63;
  const int g     = lane >> 4;
  const int j16   = lane & 15;
  const int wmask = bw & (NW - 1);

  // ---------------- Phase 1: QKV (per-head ownership) ----------------
  bf16x8 xa[4][4];
#pragma unroll
  for (int tt = 0; tt < 4; ++tt) {
    const int t = tt * 16 + j16;
#pragma unroll
    for (int kt = 0; kt < 4; ++kt) {
      B8 u;
      if (t < T49) {
        const float* p = x + (size_t)bw * (T49 * CDIM) + t * CDIM + kt * 32 + g * 8;
        const float4 v0 = *(const float4*)p;
        const float4 v1 = *(const float4*)(p + 4);
        u.u[0] = pk2(v0.x, v0.y); u.u[1] = pk2(v0.z, v0.w);
        u.u[2] = pk2(v1.x, v1.y); u.u[3] = pk2(v1.z, v1.w);
      } else {
        u.u[0] = u.u[1] = u.u[2] = u.u[3] = 0u;
      }
      xa[tt][kt] = u.v;
    }
  }

  unsigned int pkV[2][4][2];  // [d-tile vi][tt][pair]: pairs along token (natural D[t][c])

#pragma unroll
  for (int ni = 0; ni < 6; ++ni) {
    const int ct = (ni < 2) ? (wv * 2 + ni)
                 : (ni < 4) ? (8 + wv * 2 + (ni - 2))
                            : (16 + wv * 2 + (ni - 4));
    bf16x8 wf[4];                                     // w frag: row c=ct*16+j16, k=kt*32+g*8..+7
#pragma unroll
    for (int kt = 0; kt < 4; ++kt)
      wf[kt] = *(const bf16x8*)(wq + (ct * 16 + j16) * CDIM + kt * 32 + g * 8);

    if (ni < 4) {
      // swapped: D[c][t]; 4 regs = consecutive channels -> b64 store into [t][d]
      const int  c0  = ct * 16 + g * 4;
      const bool isQ = (ni < 2);
      float4 b4 = *(const float4*)(b_qkv + c0);
      const float sc = isQ ? SCALEF : 1.0f;           // fold q-scale into Q
      const int d0 = c0 & 31;
      char* base = smem + (isQ ? Q_BASE : KO_BASE) + wv * 4096;
#pragma unroll
      for (int tt = 0; tt < 4; ++tt) {
        f32x4 acc = {0.f, 0.f, 0.f, 0.f};
#pragma unroll
        for (int kt = 0; kt < 4; ++kt)
          acc = __builtin_amdgcn_mfma_f32_16x16x32_bf16(wf[kt], xa[tt][kt], acc, 0, 0, 0);
        const int t = tt * 16 + j16;
        const uint2 w2 = make_uint2(pk2(fmaf(acc[0], sc, b4.x * sc), fmaf(acc[1], sc, b4.y * sc)),
                                    pk2(fmaf(acc[2], sc, b4.z * sc), fmaf(acc[3], sc, b4.w * sc)));
        *(uint2*)(base + t * 64 + ((d0 * 2) ^ ((t & 3) << 4))) = w2;
      }
    } else {
      // V natural: D[t][c] -> registers (pairs along token)
      const int   vi   = ni - 4;
      const float bias = b_qkv[ct * 16 + j16];
#pragma unroll
      for (int tt = 0; tt < 4; ++tt) {
        f32x4 acc = {0.f, 0.f, 0.f, 0.f};
#pragma unroll
        for (int kt = 0; kt < 4; ++kt)
          acc = __builtin_amdgcn_mfma_f32_16x16x32_bf16(xa[tt][kt], wf[kt], acc, 0, 0, 0);
        pkV[vi][tt][0] = pk2(acc[0] + bias, acc[1] + bias);
        pkV[vi][tt][1] = pk2(acc[2] + bias, acc[3] + bias);
      }
    }
  }
  // NO barrier: kb/qb loads below read only this wave's own writes.

  // ---------------- Prologue: kb, qb from own LDS; va from pkV ----------------
  const int gh   = g >> 1;
  const int srcA = (((2 * g    ) & 3) << 4) | j16;
  const int srcB = (((2 * g + 1) & 3) << 4) | j16;

  const char* Kb = smem + KO_BASE + wv * 4096;
  const char* Qb = smem + Q_BASE  + wv * 4096;
  bf16x8 kb[4], qb[4];
#pragma unroll
  for (int mt = 0; mt < 4; ++mt) {
    const int t = mt * 16 + j16;
    kb[mt] = *(const bf16x8*)(Kb + t * 64 + ((g * 16) ^ ((t & 3) << 4)));
    qb[mt] = *(const bf16x8*)(Qb + t * 64 + ((g * 16) ^ ((t & 3) << 4)));
  }

  // va[dt][ks] elem e wants V[key=ks*32+8g+e][d=dt*16+j16]: source tile
  // tt = 2ks + (g>>1), lane (2g+(e>>2))&3 group, pair (e&3)>>1.
  bf16x8 va[2][2];
#pragma unroll
  for (int dt = 0; dt < 2; ++dt)
#pragma unroll
    for (int ks = 0; ks < 2; ++ks) {
      const unsigned int a0  = (unsigned)__shfl((int)pkV[dt][2 * ks    ][0], srcA, 64);
      const unsigned int a0h = (unsigned)__shfl((int)pkV[dt][2 * ks + 1][0], srcA, 64);
      const unsigned int a1  = (unsigned)__shfl((int)pkV[dt][2 * ks    ][1], srcA, 64);
      const unsigned int a1h = (unsigned)__shfl((int)pkV[dt][2 * ks + 1][1], srcA, 64);
      const unsigned int b0  = (unsigned)__shfl((int)pkV[dt][2 * ks    ][0], srcB, 64);
      const unsigned int b0h = (unsigned)__shfl((int)pkV[dt][2 * ks + 1][0], srcB, 64);
      const unsigned int b1  = (unsigned)__shfl((int)pkV[dt][2 * ks    ][1], srcB, 64);
      const unsigned int b1h = (unsigned)__shfl((int)pkV[dt][2 * ks + 1][1], srcB, 64);
      B8 u;
      u.u[0] = gh ? a0h : a0;
      u.u[1] = gh ? a1h : a1;
      u.u[2] = gh ? b0h : b0;
      u.u[3] = gh ? b1h : b1;
      va[dt][ks] = u.v;
    }

  __syncthreads();   // all Q/K reads done in-registers -> O may overwrite K region

  // ---------------- Phases 2+3 merged, per q-tile nt (wave = head) ----------------
  char*        Ob  = smem + KO_BASE;
  const float* mwb = maskp + wmask * 4096;

#pragma unroll
  for (int nt = 0; nt < 4; ++nt) {
    const float* mp = mwb + (nt * 16 + j16) * 64 + g * 4;
    float4 m4[4];
#pragma unroll
    for (int mt = 0; mt < 4; ++mt) m4[mt] = *(const float4*)(mp + mt * 16);

    const f32x4 zero = {0.f, 0.f, 0.f, 0.f};
    float v[4][4];
#pragma unroll
    for (int mt = 0; mt < 4; ++mt) {
      const f32x4 s = __builtin_amdgcn_mfma_f32_16x16x32_bf16(kb[mt], qb[nt], zero, 0, 0, 0);
      // mask is pre-shifted by row max: exp directly, no max pass
      v[mt][0] = __expf(s[0] + m4[mt].x); v[mt][1] = __expf(s[1] + m4[mt].y);
      v[mt][2] = __expf(s[2] + m4[mt].z); v[mt][3] = __expf(s[3] + m4[mt].w);
    }
    // denominator chain (overlaps P-redistribute + PV below)
    float sr[8];
#pragma unroll
    for (int mt = 0; mt < 4; ++mt) {
      sr[2 * mt]     = v[mt][0] + v[mt][1];
      sr[2 * mt + 1] = v[mt][2] + v[mt][3];
    }
    float sum = ((sr[0] + sr[1]) + (sr[2] + sr[3])) + ((sr[4] + sr[5]) + (sr[6] + sr[7]));
    sum += __shfl_xor(sum, 16, 64);
    sum += __shfl_xor(sum, 32, 64);
    const float inv = 1.0f / sum;

    // P^T raw (unnormalized): pairs along key, 8 regs
    unsigned int pkn[4][2];
#pragma unroll
    for (int mt = 0; mt < 4; ++mt) {
      pkn[mt][0] = pk2(v[mt][0], v[mt][1]);
      pkn[mt][1] = pk2(v[mt][2], v[mt][3]);
    }

    // redistribute P^T + PV MFMAs
    f32x4 oacc[2] = {{0.f,0.f,0.f,0.f},{0.f,0.f,0.f,0.f}};
#pragma unroll
    for (int ks = 0; ks < 2; ++ks) {
      const unsigned int p00 = (unsigned)__shfl((int)pkn[2*ks  ][0], srcA, 64);
      const unsigned int p10 = (unsigned)__shfl((int)pkn[2*ks+1][0], srcA, 64);
      const unsigned int p01 = (unsigned)__shfl((int)pkn[2*ks  ][1], srcA, 64);
      const unsigned int p11 = (unsigned)__shfl((int)pkn[2*ks+1][1], srcA, 64);
      const unsigned int q00 = (unsigned)__shfl((int)pkn[2*ks  ][0], srcB, 64);
      const unsigned int q10 = (unsigned)__shfl((int)pkn[2*ks+1][0], srcB, 64);
      const unsigned int q01 = (unsigned)__shfl((int)pkn[2*ks  ][1], srcB, 64);
      const unsigned int q11 = (unsigned)__shfl((int)pkn[2*ks+1][1], srcB, 64);
      B8 bf;
      bf.u[0] = gh ? p10 : p00;
      bf.u[1] = gh ? p11 : p01;
      bf.u[2] = gh ? q10 : q00;
      bf.u[3] = gh ? q11 : q01;
#pragma unroll
      for (int dt = 0; dt < 2; ++dt)
        oacc[dt] = __builtin_amdgcn_mfma_f32_16x16x32_bf16(va[dt][ks], bf.v, oacc[dt], 0, 0, 0);
    }

    // deferred normalization: O = inv * (P_raw . V); lane's j16 == q on both sides
    const int to = nt * 16 + j16;
    const int sw = (to & 7) << 5;
#pragma unroll
    for (int dt = 0; dt < 2; ++dt) {
      const int ch0 = wv * 32 + dt * 16 + g * 4;
      const uint2 w2 = make_uint2(pk2(oacc[dt][0] * inv, oacc[dt][1] * inv),
                                  pk2(oacc[dt][2] * inv, oacc[dt][3] * inv));
      *(uint2*)(Ob + to * 256 + ((ch0 * 2) ^ sw)) = w2;
    }
  }
  __syncthreads();

  // ---------------- Phase 4: out = O @ wp^T + b ----------------
  {
    const char* Ob2 = smem + KO_BASE;
    bf16x8 oa[4][4];
#pragma unroll
    for (int mt = 0; mt < 4; ++mt) {
      const int t = mt * 16 + j16;
      const int sw = (t & 7) << 5;
#pragma unroll
      for (int kt = 0; kt < 4; ++kt)
        oa[mt][kt] = *(const bf16x8*)(Ob2 + t * 256 + ((kt * 64 + g * 16) ^ sw));
    }
    float* ob = out + (size_t)bw * (T49 * CDIM);
#pragma unroll
    for (int ntl = 0; ntl < 2; ++ntl) {
      const int c = (wv * 2 + ntl) * 16 + j16;
      bf16x8 bfr[4];
#pragma unroll
      for (int kt = 0; kt < 4; ++kt)
        bfr[kt] = *(const bf16x8*)(wp + c * CDIM + kt * 32 + g * 8);
      const float bias = b_proj[c];
#pragma unroll
      for (int mt = 0; mt < 4; ++mt) {
        f32x4 acc = {0.f, 0.f, 0.f, 0.f};
#pragma unroll
        for (int kt = 0; kt < 4; ++kt)
          acc = __builtin_amdgcn_mfma_f32_16x16x32_bf16(oa[mt][kt], bfr[kt], acc, 0, 0, 0);
#pragma unroll
        for (int r = 0; r < 4; ++r) {
          const int t = mt * 16 + g * 4 + r;
          if (t < T49) ob[t * CDIM + c] = acc[r] + bias;
        }
      }
    }
  }
}

extern "C" void kernel_launch(void* const* d_in, const int* in_sizes, int n_in,
                              void* d_out, int out_size, void* d_ws, size_t ws_size,
                              hipStream_t stream) {
  const float* x      = (const float*)d_in[0];
  const float* mask   = (const float*)d_in[1];
  const float* w_qkv  = (const float*)d_in[2];
  const float* b_qkv  = (const float*)d_in[3];
  const float* w_proj = (const float*)d_in[4];
  const float* b_proj = (const float*)d_in[5];
  float* out = (float*)d_out;

  float* maskp = (float*)d_ws;                       // 64*64*64 f32 = 1 MB
  short* wq_bf = (short*)((char*)d_ws + 64*64*64*4); // 96 KB
  short* wp_bf = wq_bf + 3 * CDIM * CDIM;            // 32 KB

  hipLaunchKernelGGL(prep_kernel, dim3(1024), dim3(256), 0, stream,
                     w_qkv, w_proj, mask, wq_bf, wp_bf, maskp);
  hipLaunchKernelGGL(winattn_kernel, dim3(8192), dim3(256), 0, stream,
                     x, maskp, b_qkv, b_proj, wq_bf, wp_bf, out);
}